// Round 10
// baseline (213.410 us; speedup 1.0000x reference)
//
#include <hip/hip_runtime.h>
#include <cstdint>
#include <cstddef>

typedef unsigned short ushort_t;
typedef __attribute__((ext_vector_type(4))) float f32x4;
typedef __attribute__((ext_vector_type(8))) short s16x8;

#define PI_4F 0.78539816339744830962f

// round-to-nearest-even fp32 -> bf16
__device__ inline ushort_t f2bf(float f) {
  unsigned int u = __float_as_uint(f);
  u = u + 0x7fffu + ((u >> 16) & 1u);
  return (ushort_t)(u >> 16);
}

// ---------------------------------------------------------------------------
// rot matrix for one (b, n): fills M[81] (unscaled).
// ---------------------------------------------------------------------------
__device__ void rot_compute(float t, float s, float* M) {
  float xv = cosf(t) * s, yv = sinf(t) * s;
  bool pos = (t >= 0.0f), big = (s >= 1.0f), m1 = (fabsf(t) <= PI_4F);
#pragma unroll
  for (int i = 0; i < 81; ++i) M[i] = 0.0f;
  M[36 + 4] = 1.0f;
  if (pos) {
    float a = xv - yv, bb = xv * yv, c = xv + yv;
    if (m1 && big) {  // pb1
      M[0] = a; M[1] = 1 - a;
      M[9 + 1] = 1 - yv; M[9 + 2] = yv;
      M[18 + 2] = a; M[18 + 5] = 1 - a;
      M[27 + 0] = yv; M[27 + 3] = 1 - yv;
      M[45 + 5] = 1 - yv; M[45 + 8] = yv;
      M[54 + 3] = 1 - a; M[54 + 6] = a;
      M[63 + 6] = yv; M[63 + 7] = 1 - yv;
      M[72 + 7] = 1 - a; M[72 + 8] = a;
    } else if (m1) {  // ps1
      float d = a * c, e = a + c;
      M[0] = d; M[1] = a - d; M[3] = c - d; M[4] = 1 - e + d;
      M[9 + 1] = xv - bb; M[9 + 2] = bb; M[9 + 4] = 1 - c + bb; M[9 + 5] = yv - bb;
      M[18 + 1] = c - d; M[18 + 2] = d; M[18 + 4] = 1 - e + d; M[18 + 5] = a - d;
      M[27 + 0] = bb; M[27 + 1] = yv - bb; M[27 + 3] = xv - bb; M[27 + 4] = 1 - c + bb;
      M[45 + 4] = 1 - c + bb; M[45 + 5] = xv - bb; M[45 + 7] = yv - bb; M[45 + 8] = bb;
      M[54 + 3] = a - d; M[54 + 4] = 1 - e + d; M[54 + 6] = d; M[54 + 7] = c - d;
      M[63 + 3] = yv - bb; M[63 + 4] = 1 - c + bb; M[63 + 6] = bb; M[63 + 7] = xv - bb;
      M[72 + 4] = 1 - e + d; M[72 + 5] = c - d; M[72 + 7] = a - d; M[72 + 8] = d;
    } else {  // pb2 == ps2
      M[0] = a; M[1] = 1 - a;
      M[9 + 1] = xv - bb; M[9 + 2] = bb; M[9 + 4] = 1 - c + bb; M[9 + 5] = yv - bb;
      M[18 + 2] = a; M[18 + 5] = 1 - a;
      M[27 + 0] = bb; M[27 + 1] = yv - bb; M[27 + 3] = xv - bb; M[27 + 4] = 1 - c + bb;
      M[45 + 4] = 1 - c + bb; M[45 + 5] = xv - bb; M[45 + 7] = yv - bb; M[45 + 8] = bb;
      M[54 + 3] = 1 - a; M[54 + 6] = a;
      M[63 + 3] = yv - bb; M[63 + 4] = 1 - c + bb; M[63 + 6] = bb; M[63 + 7] = xv - bb;
      M[72 + 7] = 1 - a; M[72 + 8] = a;
    }
  } else {
    float yp = -yv;
    float ap = xv - yp, bp = xv * yp, cp = xv + yp;
    if (m1 && big) {  // nb1
      M[0] = cp; M[3] = 1 - cp;
      M[9 + 0] = yp; M[9 + 1] = 1 - yp;
      M[18 + 1] = 1 - cp; M[18 + 2] = cp;
      M[27 + 3] = 1 - yp; M[27 + 6] = yp;
      M[45 + 2] = yp; M[45 + 5] = 1 - yp;
      M[54 + 6] = cp; M[54 + 7] = 1 - cp;
      M[63 + 7] = 1 - yp; M[63 + 8] = yp;
      M[72 + 5] = 1 - cp; M[72 + 8] = cp;
    } else if (m1) {  // ns1
      float dp = ap * cp, ep = ap + cp;
      M[0] = dp; M[1] = cp - dp; M[3] = ap - dp; M[4] = 1 - ep + dp;
      M[9 + 0] = bp; M[9 + 1] = xv - bp; M[9 + 3] = yp - bp; M[9 + 4] = 1 - cp + bp;
      M[18 + 1] = ap - dp; M[18 + 2] = dp; M[18 + 4] = 1 - ep + dp; M[18 + 5] = cp - dp;
      M[27 + 1] = yp - bp; M[27 + 2] = bp; M[27 + 4] = 1 - cp + bp; M[27 + 5] = xv - bp;
      M[45 + 3] = xv - bp; M[45 + 4] = 1 - cp + bp; M[45 + 6] = bp; M[45 + 7] = yp - bp;
      M[54 + 3] = cp - dp; M[54 + 4] = 1 - ep + dp; M[54 + 6] = dp; M[54 + 7] = ap - dp;
      M[63 + 4] = 1 - cp + bp; M[63 + 5] = yp - bp; M[63 + 7] = xv - bp; M[63 + 8] = bp;
      M[72 + 4] = 1 - ep + dp; M[72 + 5] = ap - dp; M[72 + 7] = cp - dp; M[72 + 8] = dp;
    } else {  // nb2 == ns2
      M[0] = cp; M[3] = 1 - cp;
      M[9 + 0] = bp; M[9 + 1] = xv - bp; M[9 + 3] = yp - bp; M[9 + 4] = 1 - cp + bp;
      M[18 + 1] = 1 - cp; M[18 + 2] = cp;
      M[27 + 3] = xv - bp; M[27 + 4] = 1 - cp + bp; M[27 + 6] = bp; M[27 + 7] = yp - bp;
      M[45 + 1] = yp - bp; M[45 + 2] = bp; M[45 + 4] = 1 - cp + bp; M[45 + 5] = xv - bp;
      M[54 + 6] = cp; M[54 + 7] = 1 - cp;
      M[63 + 4] = 1 - cp + bp; M[63 + 5] = yp - bp; M[63 + 7] = xv - bp; M[63 + 8] = bp;
      M[72 + 5] = 1 - cp; M[72 + 8] = cp;
    }
  }
}

// ---------------------------------------------------------------------------
// Fused prep kernel (unchanged from R5, proven).
//   blocks 0..255    = wt: block (o2, bq): o = {o2*2, o2*2+1}, b = bq*8..+7.
//   blocks 256..4351 = transpose: x [b][c][h][w] fp32 -> xpad bf16 + borders.
// ---------------------------------------------------------------------------
__global__ __launch_bounds__(256) void prep_kernel(
    const float* __restrict__ x, const float* __restrict__ weight,
    const float* __restrict__ thetas, const float* __restrict__ scales,
    const float* __restrict__ lambdas, ushort_t* __restrict__ xpad,
    ushort_t* __restrict__ wtout) {
  __shared__ __align__(16) char smem[32 * 81 * 4];  // 10368 B >= transpose's 8704
  const int bi = blockIdx.x;
  const int t = threadIdx.x;

  if (bi < 256) {
    // ---- weight-transform part ----
    float* rotl = (float*)smem;  // [32][81]
    const int o2 = bi & 127, bq = bi >> 7;  // bq in 0..1 -> 8 b each
    const int half = t >> 7, tloc = t & 127;
    const int o = o2 * 2 + half;
    const int c = tloc * 2;
    float wv0[4][9], wv1[4][9];
#pragma unroll
    for (int n = 0; n < 4; ++n) {
      const float* wp = weight + (((size_t)(n * 256 + o)) * 256 + c) * 9;
#pragma unroll
      for (int j = 0; j < 9; ++j) { wv0[n][j] = wp[j]; wv1[n][j] = wp[9 + j]; }
    }
    if (t < 32) {
      int gid = bq * 32 + t;  // (b*4 + n) for b = bq*8 + t/4, n = t%4
      float M[81];
      rot_compute(thetas[gid], scales[gid], M);
      float lam = lambdas[gid];
#pragma unroll
      for (int i = 0; i < 81; ++i) rotl[t * 81 + i] = M[i] * lam;
    }
    __syncthreads();
#pragma unroll
    for (int bl = 0; bl < 8; ++bl) {
      const int b = bq * 8 + bl;
#pragma unroll
      for (int i = 0; i < 9; ++i) {
        float a0 = 0.0f, a1 = 0.0f;
#pragma unroll
        for (int n = 0; n < 4; ++n) {
          const float* r = &rotl[(bl * 4 + n) * 81 + i * 9];
#pragma unroll
          for (int j = 0; j < 9; ++j) {
            a0 = fmaf(r[j], wv0[n][j], a0);
            a1 = fmaf(r[j], wv1[n][j], a1);
          }
        }
        unsigned int word = (unsigned int)f2bf(a0) | ((unsigned int)f2bf(a1) << 16);
        *(unsigned int*)&wtout[((size_t)((b * 9 + i) * 256 + o)) * 256 + c] = word;
      }
    }
  } else {
    // ---- transpose part ----
    ushort_t (*tile)[68] = (ushort_t(*)[68])smem;
    const int bi2 = bi - 256;
    const int b = bi2 >> 8, ct = (bi2 >> 6) & 3, st = bi2 & 63;
    const int c0 = ct * 64;
    const float* xb = x + ((size_t)(b * 256 + c0)) * 4096 + st * 64;
#pragma unroll
    for (int k = 0; k < 4; ++k) {
      int idx = t + 256 * k;            // (c_l 0..63) x (w4 0,4,..60)
      int c_l = idx >> 4, w4 = (idx & 15) * 4;
      float4 v = *(const float4*)&xb[(size_t)c_l * 4096 + w4];
      tile[w4 + 0][c_l] = f2bf(v.x);
      tile[w4 + 1][c_l] = f2bf(v.y);
      tile[w4 + 2][c_l] = f2bf(v.z);
      tile[w4 + 3][c_l] = f2bf(v.w);
    }
    __syncthreads();
    const int c4 = (t & 15) * 4, wl = t >> 4;
    const size_t rowbase = (size_t)(b * 4356 + (st + 1) * 66) * 256 + c0;
#pragma unroll
    for (int k = 0; k < 4; ++k) {
      int w = wl + 16 * k;
      uint2 v = *(const uint2*)&tile[w][c4];
      *(uint2*)&xpad[rowbase + (size_t)(w + 1) * 256 + c4] = v;
    }
    // fused border zeroing
    if (t < 32) {
      int w = (t & 16) ? 65 : 0;
      int cc = (t & 15) * 4;
      *(uint2*)&xpad[rowbase + (size_t)w * 256 + cc] = make_uint2(0u, 0u);
    }
    if (st == 0 || st == 63) {
      const int h = (st == 0) ? 0 : 65;
      const size_t hb = (size_t)(b * 4356 + h * 66) * 256 + c0;
      for (int idx = t; idx < 66 * 16; idx += 256) {
        int w = idx >> 4, cc = (idx & 15) * 4;
        *(uint2*)&xpad[hb + (size_t)w * 256 + cc] = make_uint2(0u, 0u);
      }
    }
  }
}

// ---------------------------------------------------------------------------
// Kernel 3: implicit-GEMM conv, bf16 MFMA 16x16x32 — m201-style 8-PHASE
// schedule on the proven R9 geometry (256 o x 256 hw tile, 512 thr / 8 waves
// as 2M x 4N, 128x64 per wave, 1 block/CU).
// K-tile = 64 c; iteration = 2 K-tiles = 8 phases. Half-tile = one 32-c chunk
// of A or B = 16 KB with the EXACT R9 buffer layout + cg8 source swizzle +
// aoff/boff read pattern (measured 0 bank conflicts) — R8's conflict failure
// mode excluded by construction. 8 static buffers: {A,B} x dbuf(k&1) x chunk.
// Per phase: {4-8 ds_read ∥ stage 1 half-tile (2 gload_lds)} -> barrier ->
// lgkmcnt(0)+sched_barrier(0) [rule #18] -> setprio(1) 16 MFMA setprio(0) ->
// barrier; vmcnt(6) at every 2-phase group end (counted: 3 half-tiles in
// flight). Residency invariant: at each group boundary, resident-through =
// issued-3 = exactly the next group's pair. Overwrite safety: each stage
// target's readers completed >=1 barrier earlier (traced for all 8 slots).
// Tail (iter 17): stages for H>143 dropped; waits tighten 6 -> 4 -> 0.
// ---------------------------------------------------------------------------
__device__ inline void gload16(const ushort_t* g, ushort_t* l) {
  __builtin_amdgcn_global_load_lds(
      (const __attribute__((address_space(1))) unsigned int*)g,
      (__attribute__((address_space(3))) unsigned int*)l, 16, 0, 0);
}

#define GROUP(ACUR, BCUR, S1, S2, VN)                                          \
  do {                                                                         \
    s16x8 bfr[4], afr[4];                                                      \
    _Pragma("unroll") for (int ni = 0; ni < 4; ++ni)                           \
        bfr[ni] = *(const s16x8*)(BCUR + boff + ni * 512);                     \
    _Pragma("unroll") for (int m = 0; m < 4; ++m)                              \
        afr[m] = *(const s16x8*)(ACUR + aoff + m * 512);                       \
    S1;                                                                        \
    __builtin_amdgcn_s_barrier();                                              \
    asm volatile("s_waitcnt lgkmcnt(0)" ::: "memory");                         \
    __builtin_amdgcn_sched_barrier(0);                                         \
    __builtin_amdgcn_s_setprio(1);                                             \
    _Pragma("unroll") for (int m = 0; m < 4; ++m)                              \
        _Pragma("unroll") for (int ni = 0; ni < 4; ++ni)                       \
            acc[m][ni] = __builtin_amdgcn_mfma_f32_16x16x32_bf16(              \
                afr[m], bfr[ni], acc[m][ni], 0, 0, 0);                         \
    __builtin_amdgcn_s_setprio(0);                                             \
    __builtin_amdgcn_s_barrier();                                              \
    _Pragma("unroll") for (int m = 0; m < 4; ++m)                              \
        afr[m] = *(const s16x8*)(ACUR + aoff + (4 + m) * 512);                 \
    S2;                                                                        \
    __builtin_amdgcn_s_barrier();                                              \
    asm volatile("s_waitcnt lgkmcnt(0)" ::: "memory");                         \
    __builtin_amdgcn_sched_barrier(0);                                         \
    __builtin_amdgcn_s_setprio(1);                                             \
    _Pragma("unroll") for (int m = 0; m < 4; ++m)                              \
        _Pragma("unroll") for (int ni = 0; ni < 4; ++ni)                       \
            acc[4 + m][ni] = __builtin_amdgcn_mfma_f32_16x16x32_bf16(          \
                afr[m], bfr[ni], acc[4 + m][ni], 0, 0, 0);                     \
    __builtin_amdgcn_s_setprio(0);                                             \
    asm volatile("s_waitcnt vmcnt(" #VN ")" ::: "memory");                     \
    __builtin_amdgcn_s_barrier();                                              \
  } while (0)

__global__ __launch_bounds__(512, 2) void conv_kernel(
    const ushort_t* __restrict__ xpad, const ushort_t* __restrict__ wt,
    float* __restrict__ out) {
  // 8 static 16 KB buffers: {A,B} x dbuf x chunk = 128 KB total
  __shared__ __align__(16) ushort_t A00[8192], A01[8192], A10[8192], A11[8192];
  __shared__ __align__(16) ushort_t B00[8192], B01[8192], B10[8192], B11[8192];

  const int id = blockIdx.x;            // 0..255
  const int xcd = id & 7;
  const int jj = id >> 3;               // 0..31 within XCD
  const int b = xcd * 2 + (jj >> 4);    // 2 batches per XCD
  const int ntile = jj & 15;            // 16 hw-tiles of 256 (4 h-rows)

  const int t = threadIdx.x;            // 0..511
  const int wave = t >> 6, lane = t & 63;
  const int wm = wave & 1, wn = wave >> 1;   // wave tile: 128 o x 64 hw
  const int lr = lane & 15, lq = lane >> 4;
  const int h0 = ntile * 4;

  const ushort_t* wt_b = wt + (size_t)b * 589824;     // 9*256*256
  const ushort_t* xp_b = xpad + (size_t)b * 1115136;  // 4356*256

  const int lrow = t >> 2;                           // 0..127
  const int cg8 = (((t & 3) ^ ((t >> 3) & 3)) * 8);  // swizzled global 16B chunk
  const int rsw = (lr >> 1) & 3;
  const int aoff = (wm * 128 + lr) * 32 + ((lq ^ rsw) * 8);
  const int boff = (wn * 64 + lr) * 32 + ((lq ^ rsw) * 8);

  f32x4 acc[8][4];
#pragma unroll
  for (int i = 0; i < 8; ++i)
#pragma unroll
    for (int j2 = 0; j2 < 4; ++j2) acc[i][j2] = (f32x4)(0.0f);

  // half-tile stagers: K-tile k (0..35), chunk c (0,1). tap = k>>2.
  auto stage_A = [&](int k, int c, ushort_t* Ad) {
    const int tap = k >> 2;
    const int c0k = ((k & 3) << 6) + (c << 5);
    const ushort_t* ga = wt_b + ((size_t)(tap * 256 + lrow)) * 256 + c0k + cg8;
    gload16(ga, Ad + wave * 512);
    gload16(ga + 128 * 256, Ad + 4096 + wave * 512);
  };
  auto stage_B = [&](int k, int c, ushort_t* Bd) {
    const int tap = k >> 2;
    const int c0k = ((k & 3) << 6) + (c << 5);
    const int kh = tap / 3, kw = tap - kh * 3;
    const int sp = (h0 + (lrow >> 6) + kh) * 66 + kw + (lrow & 63);
    gload16(xp_b + (size_t)sp * 256 + c0k + cg8, Bd + wave * 512);
    gload16(xp_b + (size_t)(sp + 132) * 256 + c0k + cg8, Bd + 4096 + wave * 512);
  };

  // prologue: H0..H4 = A(0,c0), B(0,c0), A(0,c1), B(0,c1), A(1,c0);
  // vmcnt(6) -> H0,H1 resident (exactly group-1's pair), 3 half-tiles in flight
  stage_A(0, 0, A00);
  stage_B(0, 0, B00);
  stage_A(0, 1, A01);
  stage_B(0, 1, B01);
  stage_A(1, 0, A10);
  asm volatile("s_waitcnt vmcnt(6)" ::: "memory");
  __builtin_amdgcn_s_barrier();

  // 17 steady iterations (K-tiles 0..33), 8 phases each, stage lead = 5
#pragma unroll 1
  for (int i = 0; i < 17; ++i) {
    const int k0 = 2 * i;
    GROUP(A00, B00, stage_B(k0 + 1, 0, B10), stage_A(k0 + 1, 1, A11), 6);
    GROUP(A01, B01, stage_B(k0 + 1, 1, B11), stage_A(k0 + 2, 0, A00), 6);
    GROUP(A10, B10, stage_B(k0 + 2, 0, B00), stage_A(k0 + 2, 1, A01), 6);
    GROUP(A11, B11, stage_B(k0 + 2, 1, B01), stage_A(k0 + 3, 0, A10), 6);
  }
  // tail iteration (K-tiles 34, 35): stage only H<=143; waits tighten 6->4->0
  GROUP(A00, B00, stage_B(35, 0, B10), stage_A(35, 1, A11), 6);
  GROUP(A01, B01, stage_B(35, 1, B11), ((void)0), 4);
  GROUP(A10, B10, ((void)0), ((void)0), 0);
  GROUP(A11, B11, ((void)0), ((void)0), 0);

  // Epilogue. C/D layout (m89): col(n) = lane&15, row(m) = (lane>>4)*4 + reg
  float* ob = out + ((size_t)(b * 256 + wm * 128)) * 4096 + ntile * 256 + wn * 64 + lr;
#pragma unroll
  for (int mi = 0; mi < 8; ++mi)
#pragma unroll
    for (int r = 0; r < 4; ++r) {
      float* orow = ob + (size_t)(mi * 16 + lq * 4 + r) * 4096;
#pragma unroll
      for (int ni = 0; ni < 4; ++ni) orow[ni * 16] = acc[mi][ni][r];
    }
}

// ---------------------------------------------------------------------------
extern "C" void kernel_launch(void* const* d_in, const int* in_sizes, int n_in,
                              void* d_out, int out_size, void* d_ws, size_t ws_size,
                              hipStream_t stream) {
  const float* x = (const float*)d_in[0];       // [16,256,64,64]
  const float* thetas = (const float*)d_in[1];  // [16,4]
  const float* scales = (const float*)d_in[2];  // [16,4]
  const float* lambdas = (const float*)d_in[3]; // [16,4]
  const float* weight = (const float*)d_in[4];  // [4,256,256,3,3]
  float* out = (float*)d_out;                   // [16,256,64,64]

  // workspace layout:
  //   Wt   bf16 [16][9][256][256]   @ 0         (18874368 B)
  //   xpad bf16 [16][66][66][256]   @ 18874368  (35684352 B)
  ushort_t* wt_ws = (ushort_t*)d_ws;
  ushort_t* xpad_ws = (ushort_t*)((char*)d_ws + 18874368);

  prep_kernel<<<4352, 256, 0, stream>>>(x, weight, thetas, scales, lambdas,
                                        xpad_ws, wt_ws);
  conv_kernel<<<256, 512, 0, stream>>>(xpad_ws, wt_ws, out);
}